// Round 11
// baseline (122.399 us; speedup 1.0000x reference)
//
#include <hip/hip_runtime.h>

#define NC 4
#define CS 512
#define NS 256
#define HD 512
#define H  256
#define GAMMA_F 12.0f
#define PHASE_SCALE 62.83185307179586477f   // pi / 0.05

#define KT 16        // k-steps per staging round
#define KSPLIT 8     // k-slices (32 k each)
#define ROUNDS 2     // 32 / KT

// Round 10 (resubmit; prior attempt hit GPUAcquisitionTimeout, never ran):
// round-5 block internals (proven: VGPR 64, no spill) + KSPLIT=8 for
// 4 waves/SIMD, with XCD-pinned decode: ks = bid & 7 so each XCD's
// round-robin share works on ONE k-slice (~1MB working set, fits 4MB L2).
// Round 6 showed unswizzled KSPLIT=8 thrashes L2 (FETCH 26->88MB).
// grid: 1024 blocks = 8 ks * 4 c * 8 hT * 4 tT, 256 thr
__global__ __launch_bounds__(256, 4) void score_partial(
    const float* __restrict__ heads,     // 2048 x 512
    const float* __restrict__ relations, // 2048 x 256
    const float* __restrict__ tails,     // 1024 x 512
    float* __restrict__ part)            // 8 planes of [4][512][256]
{
    __shared__ float2 sh[64][KT + 1];   // rotated head (re,im), +1 pad
    __shared__ float2 st[64][KT + 1];   // tail (re,im), +1 pad

    int bid = blockIdx.x;
    int ks  = bid & 7;            // k-slice == XCD id (round-robin heuristic)
    int idx = bid >> 3;           // 0..127
    int c   = idx & 3;            // chunk
    int rem = idx >> 2;           // 0..31
    int hT  = rem >> 2;           // 0..7
    int tT  = rem & 3;            // 0..3

    int hBase = c * CS + hT * 64;     // global head row
    int tBase = c * NS + tT * 64;     // global tail row
    int kSlice = ks * 32;             // k range [kSlice, kSlice+32)

    int tid = threadIdx.x;
    int tx = tid & 15;            // tail micro index
    int ty = tid >> 4;            // head micro index

    // staging: 64 rows x 4 lanes x 4 k-elems (float4)
    int srow = tid >> 2;          // 0..63
    int sk   = (tid & 3) * 4;     // 0,4,8,12

    const float* hrow = heads + (size_t)(hBase + srow) * HD + kSlice + sk;
    const float* rrow = relations + (size_t)(hBase + srow) * H + kSlice + sk;
    const float* trow = tails + (size_t)(tBase + srow) * HD + kSlice + sk;

    float acc[4][4];
    #pragma unroll
    for (int m = 0; m < 4; ++m)
        #pragma unroll
        for (int n = 0; n < 4; ++n) acc[m][n] = 0.f;

    for (int r = 0; r < ROUNDS; ++r) {
        int o = r * KT;
        // ---- global loads into regs ----
        float4 hre = *reinterpret_cast<const float4*>(hrow + o);
        float4 him = *reinterpret_cast<const float4*>(hrow + o + H);
        float4 rel = *reinterpret_cast<const float4*>(rrow + o);
        float4 tre = *reinterpret_cast<const float4*>(trow + o);
        float4 tim = *reinterpret_cast<const float4*>(trow + o + H);

        __syncthreads();   // previous round's LDS reads complete

        // ---- rotate heads inline, stage interleaved (re,im) ----
        {
            float s, cc;
            __sincosf(rel.x * PHASE_SCALE, &s, &cc);
            sh[srow][sk + 0] = make_float2(hre.x * cc - him.x * s,
                                           hre.x * s + him.x * cc);
            __sincosf(rel.y * PHASE_SCALE, &s, &cc);
            sh[srow][sk + 1] = make_float2(hre.y * cc - him.y * s,
                                           hre.y * s + him.y * cc);
            __sincosf(rel.z * PHASE_SCALE, &s, &cc);
            sh[srow][sk + 2] = make_float2(hre.z * cc - him.z * s,
                                           hre.z * s + him.z * cc);
            __sincosf(rel.w * PHASE_SCALE, &s, &cc);
            sh[srow][sk + 3] = make_float2(hre.w * cc - him.w * s,
                                           hre.w * s + him.w * cc);
        }
        st[srow][sk + 0] = make_float2(tre.x, tim.x);
        st[srow][sk + 1] = make_float2(tre.y, tim.y);
        st[srow][sk + 2] = make_float2(tre.z, tim.z);
        st[srow][sk + 3] = make_float2(tre.w, tim.w);

        __syncthreads();   // staging visible

        #pragma unroll
        for (int kk = 0; kk < KT; ++kk) {
            float2 hv[4], tv[4];
            hv[0] = sh[ty     ][kk];
            hv[1] = sh[ty + 16][kk];
            hv[2] = sh[ty + 32][kk];
            hv[3] = sh[ty + 48][kk];
            tv[0] = st[tx     ][kk];
            tv[1] = st[tx + 16][kk];
            tv[2] = st[tx + 32][kk];
            tv[3] = st[tx + 48][kk];
            #pragma unroll
            for (int m = 0; m < 4; ++m) {
                #pragma unroll
                for (int n = 0; n < 4; ++n) {
                    float dr = hv[m].x - tv[n].x;
                    float di = hv[m].y - tv[n].y;
                    acc[m][n] += __builtin_amdgcn_sqrtf(dr * dr + di * di);
                }
            }
        }
    }

    // epilogue: plain stores of this k-slice's partial plane
    float* plane = part + (size_t)ks * (NC * CS * NS);
    size_t cbase = (size_t)c * CS * NS;
    #pragma unroll
    for (int m = 0; m < 4; ++m) {
        int i0 = hT * 64 + ty + 16 * m;
        #pragma unroll
        for (int n = 0; n < 4; ++n) {
            int j0 = tT * 64 + tx + 16 * n;
            plane[cbase + (size_t)i0 * NS + j0] = acc[m][n];
        }
    }
}

// out = GAMMA - sum of 8 planes; 131072 threads, one float4 each
__global__ __launch_bounds__(256) void reduce_kernel(
    const float* __restrict__ part, float* __restrict__ out)
{
    const int PLANE = NC * CS * NS;   // 524288
    int idx = (blockIdx.x * 256 + threadIdx.x) * 4;
    float sx = 0.f, sy = 0.f, sz = 0.f, sw = 0.f;
    #pragma unroll
    for (int p = 0; p < KSPLIT; ++p) {
        float4 v = *reinterpret_cast<const float4*>(part + (size_t)p * PLANE + idx);
        sx += v.x; sy += v.y; sz += v.z; sw += v.w;
    }
    float4 r;
    r.x = GAMMA_F - sx;
    r.y = GAMMA_F - sy;
    r.z = GAMMA_F - sz;
    r.w = GAMMA_F - sw;
    *reinterpret_cast<float4*>(out + idx) = r;
}

extern "C" void kernel_launch(void* const* d_in, const int* in_sizes, int n_in,
                              void* d_out, int out_size, void* d_ws, size_t ws_size,
                              hipStream_t stream) {
    (void)in_sizes; (void)n_in; (void)ws_size; (void)out_size;
    const float* heads = (const float*)d_in[0];
    const float* rels  = (const float*)d_in[1];
    const float* tails = (const float*)d_in[2];
    float* part = (float*)d_ws;   // 8 planes x 2 MB = 16 MB

    score_partial<<<1024, 256, 0, stream>>>(heads, rels, tails, part);
    reduce_kernel<<<512, 256, 0, stream>>>(part, (float*)d_out);
}